// Round 6
// baseline (382.754 us; speedup 1.0000x reference)
//
#include <hip/hip_runtime.h>

#define N_NODES 50000
#define E_EDGES 800000
#define E_TOT   850000   // E + N self loops
#define IN_DIM  128
#define C1      256      // H1*HID
#define NHEAD   8
#define HID     32
#define C2      64
#define NEG     0.2f
#define NBLK    196      // ceil(50000/256)

__device__ __forceinline__ float leaky(float x){ return x > 0.f ? x : NEG * x; }
__device__ __forceinline__ float elu1(float x){ return x > 0.f ? x : __expf(x) - 1.f; }
__device__ __forceinline__ unsigned short bf16rne(float v){
    unsigned int b = __float_as_uint(v);
    b += 0x7FFFu + ((b >> 16) & 1u);
    return (unsigned short)(b >> 16);
}
__device__ __forceinline__ float bf2f(unsigned short u){
    return __uint_as_float((unsigned int)u << 16);
}

// ---------------- CSR build ----------------
__global__ void k_count(const int* __restrict__ dst, int* __restrict__ deg){
    int e = blockIdx.x * blockDim.x + threadIdx.x;
    if (e < E_EDGES) atomicAdd(&deg[dst[e]], 1);
}

__global__ __launch_bounds__(256) void k_block_scan(const int* __restrict__ deg,
                                                    int* __restrict__ rowptr,
                                                    int* __restrict__ bsum){
    __shared__ int sd[256];
    const int t = threadIdx.x;
    int i = blockIdx.x * 256 + t;
    int v = (i < N_NODES) ? (deg[i] + 1) : 0;   // +1 for self loop
    sd[t] = v;
    __syncthreads();
    #pragma unroll
    for (int off = 1; off < 256; off <<= 1){
        int u = (t >= off) ? sd[t - off] : 0;
        __syncthreads();
        sd[t] += u;
        __syncthreads();
    }
    if (i < N_NODES) rowptr[i] = sd[t] - v;     // exclusive within block
    if (t == 255) bsum[blockIdx.x] = sd[255];
}

__global__ __launch_bounds__(256) void k_scan_sums(int* __restrict__ bsum,
                                                   int* __restrict__ rowptr){
    __shared__ int sd[256];
    const int t = threadIdx.x;
    int v = (t < NBLK) ? bsum[t] : 0;
    sd[t] = v;
    __syncthreads();
    #pragma unroll
    for (int off = 1; off < 256; off <<= 1){
        int u = (t >= off) ? sd[t - off] : 0;
        __syncthreads();
        sd[t] += u;
        __syncthreads();
    }
    if (t < NBLK) bsum[t] = sd[t] - v;          // exclusive offsets
    if (t == 255) rowptr[N_NODES] = sd[255];
}

__global__ __launch_bounds__(256) void k_add_off(const int* __restrict__ bsum,
                                                 int* __restrict__ rowptr,
                                                 int* __restrict__ cursor){
    int i = blockIdx.x * 256 + threadIdx.x;
    if (i < N_NODES){
        int r = rowptr[i] + bsum[blockIdx.x];
        rowptr[i] = r;
        cursor[i] = r;
    }
}

__global__ void k_scatter(const int* __restrict__ src, const int* __restrict__ dst,
                          int* __restrict__ cursor, int* __restrict__ csr){
    int e = blockIdx.x * blockDim.x + threadIdx.x;
    if (e < E_EDGES){
        int p = atomicAdd(&cursor[dst[e]], 1);
        if (p < E_TOT) csr[p] = src[e];
    } else if (e < E_TOT){
        int nloc = e - E_EDGES;
        int p = atomicAdd(&cursor[nloc], 1);
        if (p < E_TOT) csr[p] = nloc;   // self loop
    }
}

// ---------------- GEMM1 (x@W1): 128x128 tile, 8x8 micro, fused bf16 + scores ----------------
__global__ __launch_bounds__(256) void k_gemm1(const float* __restrict__ A,
                                               const float* __restrict__ B,
                                               const float* __restrict__ a_src,
                                               const float* __restrict__ a_dst,
                                               unsigned short* __restrict__ h1b,
                                               float* __restrict__ als,
                                               float* __restrict__ ald){
    __shared__ float As[32][132];   // transposed As[k][m]; pad 132 cuts store conflicts 8->4 way
    __shared__ float Bs[32][128];
    const int t = threadIdx.x;
    const int bm0 = blockIdx.x * 128, bn0 = blockIdx.y * 128;
    const int tm = (t >> 4) << 3;
    const int tn = (t & 15) << 3;
    float acc[8][8] = {{0.f}};

    for (int kt = 0; kt < IN_DIM; kt += 32){
        #pragma unroll
        for (int p = 0; p < 4; p++){
            int idx = t + (p << 8);
            int r = idx >> 3, c = (idx & 7) << 2;
            int row = bm0 + r;
            float4 v = make_float4(0.f, 0.f, 0.f, 0.f);
            if (row < N_NODES) v = *(const float4*)(A + (size_t)row * IN_DIM + kt + c);
            As[c    ][r] = v.x;
            As[c + 1][r] = v.y;
            As[c + 2][r] = v.z;
            As[c + 3][r] = v.w;
        }
        #pragma unroll
        for (int p = 0; p < 4; p++){
            int idx = t + (p << 8);
            int r = idx >> 5, c = (idx & 31) << 2;
            *(float4*)&Bs[r][c] = *(const float4*)(B + (size_t)(kt + r) * C1 + bn0 + c);
        }
        __syncthreads();
        #pragma unroll
        for (int k = 0; k < 32; k++){
            float4 a0 = *(const float4*)&As[k][tm];
            float4 a1 = *(const float4*)&As[k][tm + 4];
            float4 b0 = *(const float4*)&Bs[k][tn];
            float4 b1 = *(const float4*)&Bs[k][tn + 4];
            float av[8] = {a0.x,a0.y,a0.z,a0.w,a1.x,a1.y,a1.z,a1.w};
            float bv[8] = {b0.x,b0.y,b0.z,b0.w,b1.x,b1.y,b1.z,b1.w};
            #pragma unroll
            for (int i = 0; i < 8; i++)
                #pragma unroll
                for (int j = 0; j < 8; j++)
                    acc[i][j] += av[i] * bv[j];
        }
        __syncthreads();
    }

    // epilogue: exact fp32 scores + bf16 store. 8 cols/thread all within one head.
    float4 s0 = *(const float4*)(a_src + bn0 + tn);
    float4 s1 = *(const float4*)(a_src + bn0 + tn + 4);
    float4 d0 = *(const float4*)(a_dst + bn0 + tn);
    float4 d1 = *(const float4*)(a_dst + bn0 + tn + 4);
    float sv[8] = {s0.x,s0.y,s0.z,s0.w,s1.x,s1.y,s1.z,s1.w};
    float dv[8] = {d0.x,d0.y,d0.z,d0.w,d1.x,d1.y,d1.z,d1.w};
    #pragma unroll
    for (int i = 0; i < 8; i++){
        float ps = 0.f, pd = 0.f;
        #pragma unroll
        for (int j = 0; j < 8; j++){
            ps += acc[i][j] * sv[j];
            pd += acc[i][j] * dv[j];
        }
        ps += __shfl_xor(ps, 1, 64); ps += __shfl_xor(ps, 2, 64);
        pd += __shfl_xor(pd, 1, 64); pd += __shfl_xor(pd, 2, 64);
        int row = bm0 + tm + i;
        if (row < N_NODES){
            if ((t & 3) == 0){
                int hd = (bn0 >> 5) + ((t & 15) >> 2);
                als[row * NHEAD + hd] = ps;
                ald[row * NHEAD + hd] = pd;
            }
            ushort4 o0, o1;
            o0.x = bf16rne(acc[i][0]); o0.y = bf16rne(acc[i][1]);
            o0.z = bf16rne(acc[i][2]); o0.w = bf16rne(acc[i][3]);
            o1.x = bf16rne(acc[i][4]); o1.y = bf16rne(acc[i][5]);
            o1.z = bf16rne(acc[i][6]); o1.w = bf16rne(acc[i][7]);
            *(ushort4*)(h1b + (size_t)row * C1 + bn0 + tn)     = o0;
            *(ushort4*)(h1b + (size_t)row * C1 + bn0 + tn + 4) = o1;
        }
    }
}

// ---------------- GEMM2 (hact@W2): 128x64 tile, 8x4 micro, fused conv2 scores ----------------
__global__ __launch_bounds__(256) void k_gemm2(const float* __restrict__ A,
                                               const float* __restrict__ B,
                                               const float* __restrict__ a_src,
                                               const float* __restrict__ a_dst,
                                               float* __restrict__ C,
                                               float* __restrict__ als,
                                               float* __restrict__ ald){
    __shared__ float As[32][132];
    __shared__ float Bs[32][64];
    const int t = threadIdx.x;
    const int bm0 = blockIdx.x * 128;
    const int tm = (t >> 4) << 3;
    const int tn = (t & 15) << 2;
    float acc[8][4] = {{0.f}};

    for (int kt = 0; kt < C1; kt += 32){
        #pragma unroll
        for (int p = 0; p < 4; p++){
            int idx = t + (p << 8);
            int r = idx >> 3, c = (idx & 7) << 2;
            int row = bm0 + r;
            float4 v = make_float4(0.f, 0.f, 0.f, 0.f);
            if (row < N_NODES) v = *(const float4*)(A + (size_t)row * C1 + kt + c);
            As[c    ][r] = v.x;
            As[c + 1][r] = v.y;
            As[c + 2][r] = v.z;
            As[c + 3][r] = v.w;
        }
        #pragma unroll
        for (int p = 0; p < 2; p++){
            int idx = t + (p << 8);
            int r = idx >> 4, c = (idx & 15) << 2;
            *(float4*)&Bs[r][c] = *(const float4*)(B + (size_t)(kt + r) * C2 + c);
        }
        __syncthreads();
        #pragma unroll
        for (int k = 0; k < 32; k++){
            float4 a0 = *(const float4*)&As[k][tm];
            float4 a1 = *(const float4*)&As[k][tm + 4];
            float4 b0 = *(const float4*)&Bs[k][tn];
            float av[8] = {a0.x,a0.y,a0.z,a0.w,a1.x,a1.y,a1.z,a1.w};
            float bv[4] = {b0.x,b0.y,b0.z,b0.w};
            #pragma unroll
            for (int i = 0; i < 8; i++)
                #pragma unroll
                for (int j = 0; j < 4; j++)
                    acc[i][j] += av[i] * bv[j];
        }
        __syncthreads();
    }

    float4 as4 = *(const float4*)(a_src + tn);
    float4 ad4 = *(const float4*)(a_dst + tn);
    #pragma unroll
    for (int i = 0; i < 8; i++){
        float ps = acc[i][0]*as4.x + acc[i][1]*as4.y + acc[i][2]*as4.z + acc[i][3]*as4.w;
        float pd = acc[i][0]*ad4.x + acc[i][1]*ad4.y + acc[i][2]*ad4.z + acc[i][3]*ad4.w;
        #pragma unroll
        for (int off = 1; off < 16; off <<= 1){
            ps += __shfl_xor(ps, off, 64);
            pd += __shfl_xor(pd, off, 64);
        }
        int row = bm0 + tm + i;
        if (row < N_NODES){
            if ((t & 15) == 0){
                als[row] = ps;
                ald[row] = pd;
            }
            float4 o = make_float4(acc[i][0], acc[i][1], acc[i][2], acc[i][3]);
            *(float4*)(C + (size_t)row * C2 + tn) = o;
        }
    }
}

// ---------------- conv1 aggregation: fixed-ref softmax (no max chain), bf16 gather, 4x ----------------
// Scores are O(1) sums of unit-normal dots: exp() is range-safe in fp32; softmax ratio
// is mathematically identical to the max-subtracted form.
__global__ __launch_bounds__(256) void k_agg1(const int* __restrict__ rowptr, const int* __restrict__ csr,
                       const unsigned short* __restrict__ h1b, const float* __restrict__ als,
                       const float* __restrict__ ald, const float* __restrict__ b1,
                       float* __restrict__ hact){
    int gid = blockIdx.x * blockDim.x + threadIdx.x;
    int node = gid >> 6, lane = gid & 63;
    if (node >= N_NODES) return;
    int h = lane >> 3;
    float ad = ald[node * NHEAD + h];
    int r0 = rowptr[node], r1 = rowptr[node + 1];
    float s = 0.f;
    float4 acc = make_float4(0.f, 0.f, 0.f, 0.f);
    int i = r0;
    for (; i + 3 < r1; i += 4){
        int sc0 = csr[i], sc1 = csr[i+1], sc2 = csr[i+2], sc3 = csr[i+3];
        float e0 = leaky(als[sc0 * NHEAD + h] + ad);
        float e1 = leaky(als[sc1 * NHEAD + h] + ad);
        float e2 = leaky(als[sc2 * NHEAD + h] + ad);
        float e3 = leaky(als[sc3 * NHEAD + h] + ad);
        ushort4 u0 = *(const ushort4*)(h1b + (size_t)sc0 * C1 + (lane << 2));
        ushort4 u1 = *(const ushort4*)(h1b + (size_t)sc1 * C1 + (lane << 2));
        ushort4 u2 = *(const ushort4*)(h1b + (size_t)sc2 * C1 + (lane << 2));
        ushort4 u3 = *(const ushort4*)(h1b + (size_t)sc3 * C1 + (lane << 2));
        float p0 = __expf(e0), p1 = __expf(e1), p2 = __expf(e2), p3 = __expf(e3);
        s += (p0 + p1) + (p2 + p3);
        acc.x += (p0*bf2f(u0.x) + p1*bf2f(u1.x)) + (p2*bf2f(u2.x) + p3*bf2f(u3.x));
        acc.y += (p0*bf2f(u0.y) + p1*bf2f(u1.y)) + (p2*bf2f(u2.y) + p3*bf2f(u3.y));
        acc.z += (p0*bf2f(u0.z) + p1*bf2f(u1.z)) + (p2*bf2f(u2.z) + p3*bf2f(u3.z));
        acc.w += (p0*bf2f(u0.w) + p1*bf2f(u1.w)) + (p2*bf2f(u2.w) + p3*bf2f(u3.w));
    }
    for (; i < r1; i++){
        int sc = csr[i];
        float e = leaky(als[sc * NHEAD + h] + ad);
        ushort4 u = *(const ushort4*)(h1b + (size_t)sc * C1 + (lane << 2));
        float p = __expf(e);
        s += p;
        acc.x += p * bf2f(u.x);
        acc.y += p * bf2f(u.y);
        acc.z += p * bf2f(u.z);
        acc.w += p * bf2f(u.w);
    }
    float sinv = 1.f / s;
    float4 b = *(const float4*)(b1 + (lane << 2));
    acc.x = elu1(acc.x * sinv + b.x);
    acc.y = elu1(acc.y * sinv + b.y);
    acc.z = elu1(acc.z * sinv + b.z);
    acc.w = elu1(acc.w * sinv + b.w);
    *(float4*)(hact + (size_t)node * C1 + (lane << 2)) = acc;
}

// ---------------- conv2 aggregation: fixed-ref softmax, 4x ----------------
__global__ __launch_bounds__(256) void k_agg2(const int* __restrict__ rowptr, const int* __restrict__ csr,
                       const float* __restrict__ h2, const float* __restrict__ als,
                       const float* __restrict__ ald, const float* __restrict__ b2,
                       float* __restrict__ out){
    int gid = blockIdx.x * blockDim.x + threadIdx.x;
    int node = gid >> 6, lane = gid & 63;
    if (node >= N_NODES) return;
    float ad = ald[node];
    int r0 = rowptr[node], r1 = rowptr[node + 1];
    float s = 0.f, acc = 0.f;
    int i = r0;
    for (; i + 3 < r1; i += 4){
        int sc0 = csr[i], sc1 = csr[i+1], sc2 = csr[i+2], sc3 = csr[i+3];
        float e0 = leaky(als[sc0] + ad);
        float e1 = leaky(als[sc1] + ad);
        float e2 = leaky(als[sc2] + ad);
        float e3 = leaky(als[sc3] + ad);
        float f0 = h2[(size_t)sc0 * C2 + lane];
        float f1 = h2[(size_t)sc1 * C2 + lane];
        float f2 = h2[(size_t)sc2 * C2 + lane];
        float f3 = h2[(size_t)sc3 * C2 + lane];
        float p0 = __expf(e0), p1 = __expf(e1), p2 = __expf(e2), p3 = __expf(e3);
        s += (p0 + p1) + (p2 + p3);
        acc += (p0*f0 + p1*f1) + (p2*f2 + p3*f3);
    }
    for (; i < r1; i++){
        int sc = csr[i];
        float e = leaky(als[sc] + ad);
        float hv = h2[(size_t)sc * C2 + lane];
        float p = __expf(e);
        s += p;
        acc += p * hv;
    }
    out[(size_t)node * C2 + lane] = elu1(acc / s + b2[lane]);
}

extern "C" void kernel_launch(void* const* d_in, const int* in_sizes, int n_in,
                              void* d_out, int out_size, void* d_ws, size_t ws_size,
                              hipStream_t stream) {
    const float* x      = (const float*)d_in[0];
    const int*   ei     = (const int*)d_in[1];
    const float* W1     = (const float*)d_in[2];
    const float* a_src1 = (const float*)d_in[3];
    const float* a_dst1 = (const float*)d_in[4];
    const float* b1     = (const float*)d_in[5];
    const float* W2     = (const float*)d_in[6];
    const float* a_src2 = (const float*)d_in[7];
    const float* a_dst2 = (const float*)d_in[8];
    const float* b2     = (const float*)d_in[9];
    float* out = (float*)d_out;

    const int* e_src = ei;
    const int* e_dst = ei + E_EDGES;

    // ---- workspace layout ----
    float* ws = (float*)d_ws;
    unsigned short* h1b = (unsigned short*)ws;            // N*256 bf16
    float* als1 = ws + (size_t)N_NODES * C1 / 2;
    float* ald1 = als1 + (size_t)N_NODES * NHEAD;
    float* hact = ald1 + (size_t)N_NODES * NHEAD;         // N*256 fp32
    float* als2 = hact + (size_t)N_NODES * C1;
    float* ald2 = als2 + N_NODES;
    float* iend = ald2 + N_NODES;
    int* deg    = (int*)iend;
    int* rowptr = deg + N_NODES;
    int* cursor = rowptr + N_NODES + 1;
    int* bsum   = cursor + N_NODES;
    int* csr    = bsum + NBLK;
    // h2 aliases h1b region (h1b dead after agg1)
    float* h2   = ws;

    // ---- CSR build ----
    hipMemsetAsync(deg, 0, N_NODES * sizeof(int), stream);
    k_count<<<(E_EDGES + 255) / 256, 256, 0, stream>>>(e_dst, deg);
    k_block_scan<<<NBLK, 256, 0, stream>>>(deg, rowptr, bsum);
    k_scan_sums<<<1, 256, 0, stream>>>(bsum, rowptr);
    k_add_off<<<NBLK, 256, 0, stream>>>(bsum, rowptr, cursor);
    k_scatter<<<(E_TOT + 255) / 256, 256, 0, stream>>>(e_src, e_dst, cursor, csr);

    // ---- conv1 ----
    k_gemm1<<<dim3(391, 2), 256, 0, stream>>>(x, W1, a_src1, a_dst1, h1b, als1, ald1);
    k_agg1<<<(N_NODES * 64 + 255) / 256, 256, 0, stream>>>(rowptr, csr, h1b, als1, ald1, b1, hact);

    // ---- conv2 ----
    k_gemm2<<<391, 256, 0, stream>>>(hact, W2, a_src2, a_dst2, h2, als2, ald2);
    k_agg2<<<(N_NODES * 64 + 255) / 256, 256, 0, stream>>>(rowptr, csr, h2, als2, ald2, b2, out);
}

// Round 7
// 363.508 us; speedup vs baseline: 1.0529x; 1.0529x over previous
//
#include <hip/hip_runtime.h>

#define N_NODES 50000
#define E_EDGES 800000
#define E_TOT   850000   // E + N self loops
#define IN_DIM  128
#define C1      256      // H1*HID
#define NHEAD   8
#define HID     32
#define C2      64
#define NEG     0.2f
#define NBLK    196      // ceil(50000/256)

__device__ __forceinline__ float leaky(float x){ return x > 0.f ? x : NEG * x; }
__device__ __forceinline__ float elu1(float x){ return x > 0.f ? x : __expf(x) - 1.f; }
__device__ __forceinline__ unsigned short bf16rne(float v){
    unsigned int b = __float_as_uint(v);
    b += 0x7FFFu + ((b >> 16) & 1u);
    return (unsigned short)(b >> 16);
}
__device__ __forceinline__ float bf2f(unsigned short u){
    return __uint_as_float((unsigned int)u << 16);
}

// ---------------- CSR build ----------------
__global__ void k_count(const int* __restrict__ dst, int* __restrict__ deg){
    int e = blockIdx.x * blockDim.x + threadIdx.x;
    if (e < E_EDGES) atomicAdd(&deg[dst[e]], 1);
}

__global__ __launch_bounds__(256) void k_block_scan(const int* __restrict__ deg,
                                                    int* __restrict__ rowptr,
                                                    int* __restrict__ bsum){
    __shared__ int sd[256];
    const int t = threadIdx.x;
    int i = blockIdx.x * 256 + t;
    int v = (i < N_NODES) ? (deg[i] + 1) : 0;   // +1 for self loop
    sd[t] = v;
    __syncthreads();
    #pragma unroll
    for (int off = 1; off < 256; off <<= 1){
        int u = (t >= off) ? sd[t - off] : 0;
        __syncthreads();
        sd[t] += u;
        __syncthreads();
    }
    if (i < N_NODES) rowptr[i] = sd[t] - v;     // exclusive within block
    if (t == 255) bsum[blockIdx.x] = sd[255];
}

__global__ __launch_bounds__(256) void k_scan_sums(int* __restrict__ bsum,
                                                   int* __restrict__ rowptr){
    __shared__ int sd[256];
    const int t = threadIdx.x;
    int v = (t < NBLK) ? bsum[t] : 0;
    sd[t] = v;
    __syncthreads();
    #pragma unroll
    for (int off = 1; off < 256; off <<= 1){
        int u = (t >= off) ? sd[t - off] : 0;
        __syncthreads();
        sd[t] += u;
        __syncthreads();
    }
    if (t < NBLK) bsum[t] = sd[t] - v;          // exclusive offsets
    if (t == 255) rowptr[N_NODES] = sd[255];
}

__global__ __launch_bounds__(256) void k_add_off(const int* __restrict__ bsum,
                                                 int* __restrict__ rowptr,
                                                 int* __restrict__ cursor){
    int i = blockIdx.x * 256 + threadIdx.x;
    if (i < N_NODES){
        int r = rowptr[i] + bsum[blockIdx.x];
        rowptr[i] = r;
        cursor[i] = r;
    }
}

__global__ void k_scatter(const int* __restrict__ src, const int* __restrict__ dst,
                          int* __restrict__ cursor, int* __restrict__ csr){
    int e = blockIdx.x * blockDim.x + threadIdx.x;
    if (e < E_EDGES){
        int p = atomicAdd(&cursor[dst[e]], 1);
        if (p < E_TOT) csr[p] = src[e];
    } else if (e < E_TOT){
        int nloc = e - E_EDGES;
        int p = atomicAdd(&cursor[nloc], 1);
        if (p < E_TOT) csr[p] = nloc;   // self loop
    }
}

// ---------------- GEMM1 (x@W1): 128x128 tile, 8x8 micro, fused bf16 + scores ----------------
__global__ __launch_bounds__(256) void k_gemm1(const float* __restrict__ A,
                                               const float* __restrict__ B,
                                               const float* __restrict__ a_src,
                                               const float* __restrict__ a_dst,
                                               unsigned short* __restrict__ h1b,
                                               float* __restrict__ als,
                                               float* __restrict__ ald){
    __shared__ float As[32][132];   // transposed As[k][m]
    __shared__ float Bs[32][128];
    const int t = threadIdx.x;
    const int bm0 = blockIdx.x * 128, bn0 = blockIdx.y * 128;
    const int tm = (t >> 4) << 3;
    const int tn = (t & 15) << 3;
    float acc[8][8] = {{0.f}};

    for (int kt = 0; kt < IN_DIM; kt += 32){
        #pragma unroll
        for (int p = 0; p < 4; p++){
            int idx = t + (p << 8);
            int r = idx >> 3, c = (idx & 7) << 2;
            int row = bm0 + r;
            float4 v = make_float4(0.f, 0.f, 0.f, 0.f);
            if (row < N_NODES) v = *(const float4*)(A + (size_t)row * IN_DIM + kt + c);
            As[c    ][r] = v.x;
            As[c + 1][r] = v.y;
            As[c + 2][r] = v.z;
            As[c + 3][r] = v.w;
        }
        #pragma unroll
        for (int p = 0; p < 4; p++){
            int idx = t + (p << 8);
            int r = idx >> 5, c = (idx & 31) << 2;
            *(float4*)&Bs[r][c] = *(const float4*)(B + (size_t)(kt + r) * C1 + bn0 + c);
        }
        __syncthreads();
        #pragma unroll
        for (int k = 0; k < 32; k++){
            float4 a0 = *(const float4*)&As[k][tm];
            float4 a1 = *(const float4*)&As[k][tm + 4];
            float4 b0 = *(const float4*)&Bs[k][tn];
            float4 b1 = *(const float4*)&Bs[k][tn + 4];
            float av[8] = {a0.x,a0.y,a0.z,a0.w,a1.x,a1.y,a1.z,a1.w};
            float bv[8] = {b0.x,b0.y,b0.z,b0.w,b1.x,b1.y,b1.z,b1.w};
            #pragma unroll
            for (int i = 0; i < 8; i++)
                #pragma unroll
                for (int j = 0; j < 8; j++)
                    acc[i][j] += av[i] * bv[j];
        }
        __syncthreads();
    }

    // epilogue: exact fp32 scores + bf16 store. 8 cols/thread all within one head.
    float4 s0 = *(const float4*)(a_src + bn0 + tn);
    float4 s1 = *(const float4*)(a_src + bn0 + tn + 4);
    float4 d0 = *(const float4*)(a_dst + bn0 + tn);
    float4 d1 = *(const float4*)(a_dst + bn0 + tn + 4);
    float sv[8] = {s0.x,s0.y,s0.z,s0.w,s1.x,s1.y,s1.z,s1.w};
    float dv[8] = {d0.x,d0.y,d0.z,d0.w,d1.x,d1.y,d1.z,d1.w};
    #pragma unroll
    for (int i = 0; i < 8; i++){
        float ps = 0.f, pd = 0.f;
        #pragma unroll
        for (int j = 0; j < 8; j++){
            ps += acc[i][j] * sv[j];
            pd += acc[i][j] * dv[j];
        }
        ps += __shfl_xor(ps, 1, 64); ps += __shfl_xor(ps, 2, 64);
        pd += __shfl_xor(pd, 1, 64); pd += __shfl_xor(pd, 2, 64);
        int row = bm0 + tm + i;
        if (row < N_NODES){
            if ((t & 3) == 0){
                int hd = (bn0 >> 5) + ((t & 15) >> 2);
                als[row * NHEAD + hd] = ps;
                ald[row * NHEAD + hd] = pd;
            }
            ushort4 o0, o1;
            o0.x = bf16rne(acc[i][0]); o0.y = bf16rne(acc[i][1]);
            o0.z = bf16rne(acc[i][2]); o0.w = bf16rne(acc[i][3]);
            o1.x = bf16rne(acc[i][4]); o1.y = bf16rne(acc[i][5]);
            o1.z = bf16rne(acc[i][6]); o1.w = bf16rne(acc[i][7]);
            *(ushort4*)(h1b + (size_t)row * C1 + bn0 + tn)     = o0;
            *(ushort4*)(h1b + (size_t)row * C1 + bn0 + tn + 4) = o1;
        }
    }
}

// ---------------- GEMM2 (hact_b[bf16]@W2): 128x64 tile, 8x4 micro, bf16 out + scores ----------------
__global__ __launch_bounds__(256) void k_gemm2(const unsigned short* __restrict__ A,
                                               const float* __restrict__ B,
                                               const float* __restrict__ a_src,
                                               const float* __restrict__ a_dst,
                                               unsigned short* __restrict__ h2b,
                                               float* __restrict__ als,
                                               float* __restrict__ ald){
    __shared__ float As[32][132];
    __shared__ float Bs[32][64];
    const int t = threadIdx.x;
    const int bm0 = blockIdx.x * 128;
    const int tm = (t >> 4) << 3;
    const int tn = (t & 15) << 2;
    float acc[8][4] = {{0.f}};

    for (int kt = 0; kt < C1; kt += 32){
        // A tile: 128 rows x 32 cols bf16; each thread loads 16 elems (2 x ushort4-pair)
        #pragma unroll
        for (int p = 0; p < 2; p++){
            int idx = t + (p << 8);          // 0..511
            int r = idx >> 2;                // 0..127
            int c = (idx & 3) << 3;          // 0,8,16,24
            int row = bm0 + r;
            ushort4 u0 = make_ushort4(0,0,0,0), u1 = make_ushort4(0,0,0,0);
            if (row < N_NODES){
                u0 = *(const ushort4*)(A + (size_t)row * C1 + kt + c);
                u1 = *(const ushort4*)(A + (size_t)row * C1 + kt + c + 4);
            }
            As[c    ][r] = bf2f(u0.x);
            As[c + 1][r] = bf2f(u0.y);
            As[c + 2][r] = bf2f(u0.z);
            As[c + 3][r] = bf2f(u0.w);
            As[c + 4][r] = bf2f(u1.x);
            As[c + 5][r] = bf2f(u1.y);
            As[c + 6][r] = bf2f(u1.z);
            As[c + 7][r] = bf2f(u1.w);
        }
        #pragma unroll
        for (int p = 0; p < 2; p++){
            int idx = t + (p << 8);
            int r = idx >> 4, c = (idx & 15) << 2;
            *(float4*)&Bs[r][c] = *(const float4*)(B + (size_t)(kt + r) * C2 + c);
        }
        __syncthreads();
        #pragma unroll
        for (int k = 0; k < 32; k++){
            float4 a0 = *(const float4*)&As[k][tm];
            float4 a1 = *(const float4*)&As[k][tm + 4];
            float4 b0 = *(const float4*)&Bs[k][tn];
            float av[8] = {a0.x,a0.y,a0.z,a0.w,a1.x,a1.y,a1.z,a1.w};
            float bv[4] = {b0.x,b0.y,b0.z,b0.w};
            #pragma unroll
            for (int i = 0; i < 8; i++)
                #pragma unroll
                for (int j = 0; j < 4; j++)
                    acc[i][j] += av[i] * bv[j];
        }
        __syncthreads();
    }

    float4 as4 = *(const float4*)(a_src + tn);
    float4 ad4 = *(const float4*)(a_dst + tn);
    #pragma unroll
    for (int i = 0; i < 8; i++){
        float ps = acc[i][0]*as4.x + acc[i][1]*as4.y + acc[i][2]*as4.z + acc[i][3]*as4.w;
        float pd = acc[i][0]*ad4.x + acc[i][1]*ad4.y + acc[i][2]*ad4.z + acc[i][3]*ad4.w;
        #pragma unroll
        for (int off = 1; off < 16; off <<= 1){
            ps += __shfl_xor(ps, off, 64);
            pd += __shfl_xor(pd, off, 64);
        }
        int row = bm0 + tm + i;
        if (row < N_NODES){
            if ((t & 15) == 0){
                als[row] = ps;
                ald[row] = pd;
            }
            ushort4 o;
            o.x = bf16rne(acc[i][0]);
            o.y = bf16rne(acc[i][1]);
            o.z = bf16rne(acc[i][2]);
            o.w = bf16rne(acc[i][3]);
            *(ushort4*)(h2b + (size_t)row * C2 + tn) = o;
        }
    }
}

// ---------------- conv1 aggregation: fixed-ref softmax, bf16 gather, 8x MLP ----------------
__global__ __launch_bounds__(256) void k_agg1(const int* __restrict__ rowptr, const int* __restrict__ csr,
                       const unsigned short* __restrict__ h1b, const float* __restrict__ als,
                       const float* __restrict__ ald, const float* __restrict__ b1,
                       unsigned short* __restrict__ hact_b){
    int gid = blockIdx.x * blockDim.x + threadIdx.x;
    int node = gid >> 6, lane = gid & 63;
    if (node >= N_NODES) return;
    int h = lane >> 3;
    float ad = ald[node * NHEAD + h];
    int r0 = rowptr[node], r1 = rowptr[node + 1];
    float s = 0.f;
    float4 acc = make_float4(0.f, 0.f, 0.f, 0.f);
    int i = r0;
    for (; i + 7 < r1; i += 8){
        int sc0 = csr[i],   sc1 = csr[i+1], sc2 = csr[i+2], sc3 = csr[i+3];
        int sc4 = csr[i+4], sc5 = csr[i+5], sc6 = csr[i+6], sc7 = csr[i+7];
        ushort4 u0 = *(const ushort4*)(h1b + (size_t)sc0 * C1 + (lane << 2));
        ushort4 u1 = *(const ushort4*)(h1b + (size_t)sc1 * C1 + (lane << 2));
        ushort4 u2 = *(const ushort4*)(h1b + (size_t)sc2 * C1 + (lane << 2));
        ushort4 u3 = *(const ushort4*)(h1b + (size_t)sc3 * C1 + (lane << 2));
        ushort4 u4 = *(const ushort4*)(h1b + (size_t)sc4 * C1 + (lane << 2));
        ushort4 u5 = *(const ushort4*)(h1b + (size_t)sc5 * C1 + (lane << 2));
        ushort4 u6 = *(const ushort4*)(h1b + (size_t)sc6 * C1 + (lane << 2));
        ushort4 u7 = *(const ushort4*)(h1b + (size_t)sc7 * C1 + (lane << 2));
        float p0 = __expf(leaky(als[sc0 * NHEAD + h] + ad));
        float p1 = __expf(leaky(als[sc1 * NHEAD + h] + ad));
        float p2 = __expf(leaky(als[sc2 * NHEAD + h] + ad));
        float p3 = __expf(leaky(als[sc3 * NHEAD + h] + ad));
        float p4 = __expf(leaky(als[sc4 * NHEAD + h] + ad));
        float p5 = __expf(leaky(als[sc5 * NHEAD + h] + ad));
        float p6 = __expf(leaky(als[sc6 * NHEAD + h] + ad));
        float p7 = __expf(leaky(als[sc7 * NHEAD + h] + ad));
        s += ((p0 + p1) + (p2 + p3)) + ((p4 + p5) + (p6 + p7));
        acc.x += ((p0*bf2f(u0.x) + p1*bf2f(u1.x)) + (p2*bf2f(u2.x) + p3*bf2f(u3.x)))
               + ((p4*bf2f(u4.x) + p5*bf2f(u5.x)) + (p6*bf2f(u6.x) + p7*bf2f(u7.x)));
        acc.y += ((p0*bf2f(u0.y) + p1*bf2f(u1.y)) + (p2*bf2f(u2.y) + p3*bf2f(u3.y)))
               + ((p4*bf2f(u4.y) + p5*bf2f(u5.y)) + (p6*bf2f(u6.y) + p7*bf2f(u7.y)));
        acc.z += ((p0*bf2f(u0.z) + p1*bf2f(u1.z)) + (p2*bf2f(u2.z) + p3*bf2f(u3.z)))
               + ((p4*bf2f(u4.z) + p5*bf2f(u5.z)) + (p6*bf2f(u6.z) + p7*bf2f(u7.z)));
        acc.w += ((p0*bf2f(u0.w) + p1*bf2f(u1.w)) + (p2*bf2f(u2.w) + p3*bf2f(u3.w)))
               + ((p4*bf2f(u4.w) + p5*bf2f(u5.w)) + (p6*bf2f(u6.w) + p7*bf2f(u7.w)));
    }
    for (; i + 3 < r1; i += 4){
        int sc0 = csr[i], sc1 = csr[i+1], sc2 = csr[i+2], sc3 = csr[i+3];
        ushort4 u0 = *(const ushort4*)(h1b + (size_t)sc0 * C1 + (lane << 2));
        ushort4 u1 = *(const ushort4*)(h1b + (size_t)sc1 * C1 + (lane << 2));
        ushort4 u2 = *(const ushort4*)(h1b + (size_t)sc2 * C1 + (lane << 2));
        ushort4 u3 = *(const ushort4*)(h1b + (size_t)sc3 * C1 + (lane << 2));
        float p0 = __expf(leaky(als[sc0 * NHEAD + h] + ad));
        float p1 = __expf(leaky(als[sc1 * NHEAD + h] + ad));
        float p2 = __expf(leaky(als[sc2 * NHEAD + h] + ad));
        float p3 = __expf(leaky(als[sc3 * NHEAD + h] + ad));
        s += (p0 + p1) + (p2 + p3);
        acc.x += (p0*bf2f(u0.x) + p1*bf2f(u1.x)) + (p2*bf2f(u2.x) + p3*bf2f(u3.x));
        acc.y += (p0*bf2f(u0.y) + p1*bf2f(u1.y)) + (p2*bf2f(u2.y) + p3*bf2f(u3.y));
        acc.z += (p0*bf2f(u0.z) + p1*bf2f(u1.z)) + (p2*bf2f(u2.z) + p3*bf2f(u3.z));
        acc.w += (p0*bf2f(u0.w) + p1*bf2f(u1.w)) + (p2*bf2f(u2.w) + p3*bf2f(u3.w));
    }
    for (; i < r1; i++){
        int sc = csr[i];
        ushort4 u = *(const ushort4*)(h1b + (size_t)sc * C1 + (lane << 2));
        float p = __expf(leaky(als[sc * NHEAD + h] + ad));
        s += p;
        acc.x += p * bf2f(u.x);
        acc.y += p * bf2f(u.y);
        acc.z += p * bf2f(u.z);
        acc.w += p * bf2f(u.w);
    }
    float sinv = 1.f / s;
    float4 b = *(const float4*)(b1 + (lane << 2));
    ushort4 ob;
    ob.x = bf16rne(elu1(acc.x * sinv + b.x));
    ob.y = bf16rne(elu1(acc.y * sinv + b.y));
    ob.z = bf16rne(elu1(acc.z * sinv + b.z));
    ob.w = bf16rne(elu1(acc.w * sinv + b.w));
    *(ushort4*)(hact_b + (size_t)node * C1 + (lane << 2)) = ob;
}

// ---------------- conv2 aggregation: fixed-ref softmax, bf16 gather, 8x MLP ----------------
__global__ __launch_bounds__(256) void k_agg2(const int* __restrict__ rowptr, const int* __restrict__ csr,
                       const unsigned short* __restrict__ h2b, const float* __restrict__ als,
                       const float* __restrict__ ald, const float* __restrict__ b2,
                       float* __restrict__ out){
    int gid = blockIdx.x * blockDim.x + threadIdx.x;
    int node = gid >> 6, lane = gid & 63;
    if (node >= N_NODES) return;
    float ad = ald[node];
    int r0 = rowptr[node], r1 = rowptr[node + 1];
    float s = 0.f, acc = 0.f;
    int i = r0;
    for (; i + 7 < r1; i += 8){
        int sc0 = csr[i],   sc1 = csr[i+1], sc2 = csr[i+2], sc3 = csr[i+3];
        int sc4 = csr[i+4], sc5 = csr[i+5], sc6 = csr[i+6], sc7 = csr[i+7];
        float f0 = bf2f(h2b[(size_t)sc0 * C2 + lane]);
        float f1 = bf2f(h2b[(size_t)sc1 * C2 + lane]);
        float f2 = bf2f(h2b[(size_t)sc2 * C2 + lane]);
        float f3 = bf2f(h2b[(size_t)sc3 * C2 + lane]);
        float f4 = bf2f(h2b[(size_t)sc4 * C2 + lane]);
        float f5 = bf2f(h2b[(size_t)sc5 * C2 + lane]);
        float f6 = bf2f(h2b[(size_t)sc6 * C2 + lane]);
        float f7 = bf2f(h2b[(size_t)sc7 * C2 + lane]);
        float p0 = __expf(leaky(als[sc0] + ad));
        float p1 = __expf(leaky(als[sc1] + ad));
        float p2 = __expf(leaky(als[sc2] + ad));
        float p3 = __expf(leaky(als[sc3] + ad));
        float p4 = __expf(leaky(als[sc4] + ad));
        float p5 = __expf(leaky(als[sc5] + ad));
        float p6 = __expf(leaky(als[sc6] + ad));
        float p7 = __expf(leaky(als[sc7] + ad));
        s += ((p0 + p1) + (p2 + p3)) + ((p4 + p5) + (p6 + p7));
        acc += ((p0*f0 + p1*f1) + (p2*f2 + p3*f3)) + ((p4*f4 + p5*f5) + (p6*f6 + p7*f7));
    }
    for (; i + 3 < r1; i += 4){
        int sc0 = csr[i], sc1 = csr[i+1], sc2 = csr[i+2], sc3 = csr[i+3];
        float f0 = bf2f(h2b[(size_t)sc0 * C2 + lane]);
        float f1 = bf2f(h2b[(size_t)sc1 * C2 + lane]);
        float f2 = bf2f(h2b[(size_t)sc2 * C2 + lane]);
        float f3 = bf2f(h2b[(size_t)sc3 * C2 + lane]);
        float p0 = __expf(leaky(als[sc0] + ad));
        float p1 = __expf(leaky(als[sc1] + ad));
        float p2 = __expf(leaky(als[sc2] + ad));
        float p3 = __expf(leaky(als[sc3] + ad));
        s += (p0 + p1) + (p2 + p3);
        acc += (p0*f0 + p1*f1) + (p2*f2 + p3*f3);
    }
    for (; i < r1; i++){
        int sc = csr[i];
        float f = bf2f(h2b[(size_t)sc * C2 + lane]);
        float p = __expf(leaky(als[sc] + ad));
        s += p;
        acc += p * f;
    }
    out[(size_t)node * C2 + lane] = elu1(acc / s + b2[lane]);
}

extern "C" void kernel_launch(void* const* d_in, const int* in_sizes, int n_in,
                              void* d_out, int out_size, void* d_ws, size_t ws_size,
                              hipStream_t stream) {
    const float* x      = (const float*)d_in[0];
    const int*   ei     = (const int*)d_in[1];
    const float* W1     = (const float*)d_in[2];
    const float* a_src1 = (const float*)d_in[3];
    const float* a_dst1 = (const float*)d_in[4];
    const float* b1     = (const float*)d_in[5];
    const float* W2     = (const float*)d_in[6];
    const float* a_src2 = (const float*)d_in[7];
    const float* a_dst2 = (const float*)d_in[8];
    const float* b2     = (const float*)d_in[9];
    float* out = (float*)d_out;

    const int* e_src = ei;
    const int* e_dst = ei + E_EDGES;

    // ---- workspace layout ----
    float* ws = (float*)d_ws;
    unsigned short* h1b = (unsigned short*)ws;                 // N*256 bf16 (25.6MB)
    float* als1 = ws + (size_t)N_NODES * C1 / 2;
    float* ald1 = als1 + (size_t)N_NODES * NHEAD;
    unsigned short* hact_b = (unsigned short*)(ald1 + (size_t)N_NODES * NHEAD);  // N*256 bf16
    float* als2 = (float*)(hact_b + (size_t)N_NODES * C1);
    float* ald2 = als2 + N_NODES;
    float* iend = ald2 + N_NODES;
    int* deg    = (int*)iend;
    int* rowptr = deg + N_NODES;
    int* cursor = rowptr + N_NODES + 1;
    int* bsum   = cursor + N_NODES;
    int* csr    = bsum + NBLK;
    // h2b aliases h1b region (h1b dead after agg1; needs N*64*2B <= N*256*2B)
    unsigned short* h2b = h1b;

    // ---- CSR build ----
    hipMemsetAsync(deg, 0, N_NODES * sizeof(int), stream);
    k_count<<<(E_EDGES + 255) / 256, 256, 0, stream>>>(e_dst, deg);
    k_block_scan<<<NBLK, 256, 0, stream>>>(deg, rowptr, bsum);
    k_scan_sums<<<1, 256, 0, stream>>>(bsum, rowptr);
    k_add_off<<<NBLK, 256, 0, stream>>>(bsum, rowptr, cursor);
    k_scatter<<<(E_TOT + 255) / 256, 256, 0, stream>>>(e_src, e_dst, cursor, csr);

    // ---- conv1 ----
    k_gemm1<<<dim3(391, 2), 256, 0, stream>>>(x, W1, a_src1, a_dst1, h1b, als1, ald1);
    k_agg1<<<(N_NODES * 64 + 255) / 256, 256, 0, stream>>>(rowptr, csr, h1b, als1, ald1, b1, hact_b);

    // ---- conv2 ----
    k_gemm2<<<391, 256, 0, stream>>>(hact_b, W2, a_src2, a_dst2, h2b, als2, ald2);
    k_agg2<<<(N_NODES * 64 + 255) / 256, 256, 0, stream>>>(rowptr, csr, h2b, als2, ald2, b2, out);
}

// Round 8
// 324.378 us; speedup vs baseline: 1.1800x; 1.1206x over previous
//
#include <hip/hip_runtime.h>

#define N_NODES 50000
#define E_EDGES 800000
#define E_TOT   850000   // E + N self loops
#define IN_DIM  128
#define C1      256      // H1*HID
#define NHEAD   8
#define HID     32
#define C2      64
#define NEG     0.2f
#define NBLK    196      // ceil(50000/256)

typedef __attribute__((ext_vector_type(8))) short short8_t;   // 8 bf16 (4 VGPRs)
typedef __attribute__((ext_vector_type(4))) float f32x4_t;    // MFMA acc

__device__ __forceinline__ float leaky(float x){ return x > 0.f ? x : NEG * x; }
__device__ __forceinline__ float elu1(float x){ return x > 0.f ? x : __expf(x) - 1.f; }
__device__ __forceinline__ unsigned short bf16rne(float v){
    unsigned int b = __float_as_uint(v);
    b += 0x7FFFu + ((b >> 16) & 1u);
    return (unsigned short)(b >> 16);
}
__device__ __forceinline__ float bf2f(unsigned short u){
    return __uint_as_float((unsigned int)u << 16);
}

// ---------------- prep: fp32 -> bf16 casts / transposes ----------------
__global__ __launch_bounds__(256) void k_castx(const float* __restrict__ x,
                                               unsigned short* __restrict__ xb){
    int i = blockIdx.x * blockDim.x + threadIdx.x;   // one per 4 elems
    if (i < N_NODES * IN_DIM / 4){
        float4 v = *(const float4*)(x + (size_t)i * 4);
        ushort4 o;
        o.x = bf16rne(v.x); o.y = bf16rne(v.y); o.z = bf16rne(v.z); o.w = bf16rne(v.w);
        *(ushort4*)(xb + (size_t)i * 4) = o;
    }
}

// W1T[n][k] = bf16(W1[k][n]) (256x128); W2T[n][k] = bf16(W2[k][n]) (64x256)
__global__ __launch_bounds__(256) void k_wtrans(const float* __restrict__ W1,
                                                const float* __restrict__ W2,
                                                unsigned short* __restrict__ W1T,
                                                unsigned short* __restrict__ W2T){
    int i = blockIdx.x * blockDim.x + threadIdx.x;
    if (i < C1 * IN_DIM){
        int n = i >> 7, k = i & 127;
        W1T[i] = bf16rne(W1[k * C1 + n]);
    } else {
        int j = i - C1 * IN_DIM;
        if (j < C2 * C1){
            int n = j >> 8, k = j & 255;
            W2T[j] = bf16rne(W2[k * C2 + n]);
        }
    }
}

// ---------------- CSR build ----------------
__global__ void k_count(const int* __restrict__ dst, int* __restrict__ deg){
    int e = blockIdx.x * blockDim.x + threadIdx.x;
    if (e < E_EDGES) atomicAdd(&deg[dst[e]], 1);
}

__global__ __launch_bounds__(256) void k_block_scan(const int* __restrict__ deg,
                                                    int* __restrict__ rowptr,
                                                    int* __restrict__ bsum){
    __shared__ int sd[256];
    const int t = threadIdx.x;
    int i = blockIdx.x * 256 + t;
    int v = (i < N_NODES) ? (deg[i] + 1) : 0;   // +1 for self loop
    sd[t] = v;
    __syncthreads();
    #pragma unroll
    for (int off = 1; off < 256; off <<= 1){
        int u = (t >= off) ? sd[t - off] : 0;
        __syncthreads();
        sd[t] += u;
        __syncthreads();
    }
    if (i < N_NODES) rowptr[i] = sd[t] - v;
    if (t == 255) bsum[blockIdx.x] = sd[255];
}

__global__ __launch_bounds__(256) void k_scan_sums(int* __restrict__ bsum,
                                                   int* __restrict__ rowptr){
    __shared__ int sd[256];
    const int t = threadIdx.x;
    int v = (t < NBLK) ? bsum[t] : 0;
    sd[t] = v;
    __syncthreads();
    #pragma unroll
    for (int off = 1; off < 256; off <<= 1){
        int u = (t >= off) ? sd[t - off] : 0;
        __syncthreads();
        sd[t] += u;
        __syncthreads();
    }
    if (t < NBLK) bsum[t] = sd[t] - v;
    if (t == 255) rowptr[N_NODES] = sd[255];
}

__global__ __launch_bounds__(256) void k_add_off(const int* __restrict__ bsum,
                                                 int* __restrict__ rowptr,
                                                 int* __restrict__ cursor){
    int i = blockIdx.x * 256 + threadIdx.x;
    if (i < N_NODES){
        int r = rowptr[i] + bsum[blockIdx.x];
        rowptr[i] = r;
        cursor[i] = r;
    }
}

__global__ void k_scatter(const int* __restrict__ src, const int* __restrict__ dst,
                          int* __restrict__ cursor, int* __restrict__ csr){
    int e = blockIdx.x * blockDim.x + threadIdx.x;
    if (e < E_EDGES){
        int p = atomicAdd(&cursor[dst[e]], 1);
        if (p < E_TOT) csr[p] = src[e];
    } else if (e < E_TOT){
        int nloc = e - E_EDGES;
        int p = atomicAdd(&cursor[nloc], 1);
        if (p < E_TOT) csr[p] = nloc;
    }
}

// ---------------- GEMM1 (xb@W1, bf16 MFMA): 128x128 tile, fused scores + bf16 out ----------------
// 4 waves 2x2, each 64x64 out = 4x4 frags of v_mfma_f32_16x16x32_bf16, K=128 staged whole.
__global__ __launch_bounds__(256) void k_gemm1(const unsigned short* __restrict__ xb,
                                               const unsigned short* __restrict__ W1T,
                                               const float* __restrict__ a_src,
                                               const float* __restrict__ a_dst,
                                               unsigned short* __restrict__ h1b,
                                               float* __restrict__ als,
                                               float* __restrict__ ald){
    __shared__ unsigned short As[128][136];   // [m][k], pad->2-way max
    __shared__ unsigned short Bs[128][136];   // [n][k] (W1 transposed)
    const int t = threadIdx.x;
    const int lane = t & 63, w = t >> 6;
    const int wr = w >> 1, wc = w & 1;
    const int bm0 = blockIdx.x * 128, bn0 = blockIdx.y * 128;
    const int fr = lane & 15, fg = lane >> 4;

    #pragma unroll
    for (int p = 0; p < 8; p++){
        int idx = t + (p << 8);
        int r = idx >> 4, c = (idx & 15) << 3;
        int row = bm0 + r;
        int4 v = make_int4(0,0,0,0);
        if (row < N_NODES) v = *(const int4*)(xb + (size_t)row * IN_DIM + c);
        *(int4*)&As[r][c] = v;
        *(int4*)&Bs[r][c] = *(const int4*)(W1T + (size_t)(bn0 + r) * IN_DIM + c);
    }
    __syncthreads();

    f32x4_t acc[4][4] = {};
    #pragma unroll
    for (int kk = 0; kk < 4; kk++){
        short8_t af[4], bf[4];
        #pragma unroll
        for (int i = 0; i < 4; i++)
            af[i] = *(const short8_t*)&As[wr*64 + i*16 + fr][kk*32 + fg*8];
        #pragma unroll
        for (int j = 0; j < 4; j++)
            bf[j] = *(const short8_t*)&Bs[wc*64 + j*16 + fr][kk*32 + fg*8];
        #pragma unroll
        for (int i = 0; i < 4; i++)
            #pragma unroll
            for (int j = 0; j < 4; j++)
                acc[i][j] = __builtin_amdgcn_mfma_f32_16x16x32_bf16(af[i], bf[j], acc[i][j], 0, 0, 0);
    }

    // epilogue: exact fp32 scores from accumulators + bf16 store
    float asv[4], adv[4];
    #pragma unroll
    for (int j = 0; j < 4; j++){
        int col = bn0 + wc*64 + j*16 + fr;
        asv[j] = a_src[col];
        adv[j] = a_dst[col];
    }
    #pragma unroll
    for (int i = 0; i < 4; i++){
        #pragma unroll
        for (int hp = 0; hp < 2; hp++){     // head pair: j = 2hp, 2hp+1
            #pragma unroll
            for (int reg = 0; reg < 4; reg++){
                float ps = acc[i][2*hp][reg]*asv[2*hp] + acc[i][2*hp+1][reg]*asv[2*hp+1];
                float pd = acc[i][2*hp][reg]*adv[2*hp] + acc[i][2*hp+1][reg]*adv[2*hp+1];
                ps += __shfl_xor(ps, 1, 64); ps += __shfl_xor(ps, 2, 64);
                ps += __shfl_xor(ps, 4, 64); ps += __shfl_xor(ps, 8, 64);
                pd += __shfl_xor(pd, 1, 64); pd += __shfl_xor(pd, 2, 64);
                pd += __shfl_xor(pd, 4, 64); pd += __shfl_xor(pd, 8, 64);
                int R = bm0 + wr*64 + i*16 + fg*4 + reg;
                if (fr == 0 && R < N_NODES){
                    int hd = (bn0 >> 5) + wc*2 + hp;
                    als[R * NHEAD + hd] = ps;
                    ald[R * NHEAD + hd] = pd;
                }
            }
        }
        #pragma unroll
        for (int reg = 0; reg < 4; reg++){
            int R = bm0 + wr*64 + i*16 + fg*4 + reg;
            if (R < N_NODES){
                #pragma unroll
                for (int j = 0; j < 4; j++)
                    h1b[(size_t)R * C1 + bn0 + wc*64 + j*16 + fr] = bf16rne(acc[i][j][reg]);
            }
        }
    }
}

// ---------------- GEMM2 (hact_b@W2, bf16 MFMA): 128x64 tile, fused scores + bf16 out ----------------
// 4 waves split M (32 rows each), full N=64; K=256 in two 128-stages.
__global__ __launch_bounds__(256) void k_gemm2(const unsigned short* __restrict__ A,
                                               const unsigned short* __restrict__ W2T,
                                               const float* __restrict__ a_src,
                                               const float* __restrict__ a_dst,
                                               unsigned short* __restrict__ h2b,
                                               float* __restrict__ als,
                                               float* __restrict__ ald){
    __shared__ unsigned short As[128][136];
    __shared__ unsigned short Bs[64][136];
    const int t = threadIdx.x;
    const int lane = t & 63, w = t >> 6;
    const int bm0 = blockIdx.x * 128;
    const int fr = lane & 15, fg = lane >> 4;

    f32x4_t acc[2][4] = {};
    for (int kh = 0; kh < 2; kh++){
        #pragma unroll
        for (int p = 0; p < 8; p++){
            int idx = t + (p << 8);
            int r = idx >> 4, c = (idx & 15) << 3;
            int row = bm0 + r;
            int4 v = make_int4(0,0,0,0);
            if (row < N_NODES) v = *(const int4*)(A + (size_t)row * C1 + kh*128 + c);
            *(int4*)&As[r][c] = v;
        }
        #pragma unroll
        for (int p = 0; p < 4; p++){
            int idx = t + (p << 8);
            int r = idx >> 4, c = (idx & 15) << 3;
            *(int4*)&Bs[r][c] = *(const int4*)(W2T + (size_t)r * C1 + kh*128 + c);
        }
        __syncthreads();
        #pragma unroll
        for (int kk = 0; kk < 4; kk++){
            short8_t af[2], bf[4];
            #pragma unroll
            for (int i = 0; i < 2; i++)
                af[i] = *(const short8_t*)&As[w*32 + i*16 + fr][kk*32 + fg*8];
            #pragma unroll
            for (int j = 0; j < 4; j++)
                bf[j] = *(const short8_t*)&Bs[j*16 + fr][kk*32 + fg*8];
            #pragma unroll
            for (int i = 0; i < 2; i++)
                #pragma unroll
                for (int j = 0; j < 4; j++)
                    acc[i][j] = __builtin_amdgcn_mfma_f32_16x16x32_bf16(af[i], bf[j], acc[i][j], 0, 0, 0);
        }
        __syncthreads();
    }

    float asv[4], adv[4];
    #pragma unroll
    for (int j = 0; j < 4; j++){
        int col = j*16 + fr;
        asv[j] = a_src[col];
        adv[j] = a_dst[col];
    }
    #pragma unroll
    for (int i = 0; i < 2; i++){
        #pragma unroll
        for (int reg = 0; reg < 4; reg++){
            float ps = acc[i][0][reg]*asv[0] + acc[i][1][reg]*asv[1]
                     + acc[i][2][reg]*asv[2] + acc[i][3][reg]*asv[3];
            float pd = acc[i][0][reg]*adv[0] + acc[i][1][reg]*adv[1]
                     + acc[i][2][reg]*adv[2] + acc[i][3][reg]*adv[3];
            ps += __shfl_xor(ps, 1, 64); ps += __shfl_xor(ps, 2, 64);
            ps += __shfl_xor(ps, 4, 64); ps += __shfl_xor(ps, 8, 64);
            pd += __shfl_xor(pd, 1, 64); pd += __shfl_xor(pd, 2, 64);
            pd += __shfl_xor(pd, 4, 64); pd += __shfl_xor(pd, 8, 64);
            int R = bm0 + w*32 + i*16 + fg*4 + reg;
            if (fr == 0 && R < N_NODES){
                als[R] = ps;
                ald[R] = pd;
            }
            if (R < N_NODES){
                #pragma unroll
                for (int j = 0; j < 4; j++)
                    h2b[(size_t)R * C2 + j*16 + fr] = bf16rne(acc[i][j][reg]);
            }
        }
    }
}

// ---------------- conv1 aggregation: fixed-ref softmax, bf16 gather, 8x MLP ----------------
__global__ __launch_bounds__(256) void k_agg1(const int* __restrict__ rowptr, const int* __restrict__ csr,
                       const unsigned short* __restrict__ h1b, const float* __restrict__ als,
                       const float* __restrict__ ald, const float* __restrict__ b1,
                       unsigned short* __restrict__ hact_b){
    int gid = blockIdx.x * blockDim.x + threadIdx.x;
    int node = gid >> 6, lane = gid & 63;
    if (node >= N_NODES) return;
    int h = lane >> 3;
    float ad = ald[node * NHEAD + h];
    int r0 = rowptr[node], r1 = rowptr[node + 1];
    float s = 0.f;
    float4 acc = make_float4(0.f, 0.f, 0.f, 0.f);
    int i = r0;
    for (; i + 7 < r1; i += 8){
        int sc0 = csr[i],   sc1 = csr[i+1], sc2 = csr[i+2], sc3 = csr[i+3];
        int sc4 = csr[i+4], sc5 = csr[i+5], sc6 = csr[i+6], sc7 = csr[i+7];
        ushort4 u0 = *(const ushort4*)(h1b + (size_t)sc0 * C1 + (lane << 2));
        ushort4 u1 = *(const ushort4*)(h1b + (size_t)sc1 * C1 + (lane << 2));
        ushort4 u2 = *(const ushort4*)(h1b + (size_t)sc2 * C1 + (lane << 2));
        ushort4 u3 = *(const ushort4*)(h1b + (size_t)sc3 * C1 + (lane << 2));
        ushort4 u4 = *(const ushort4*)(h1b + (size_t)sc4 * C1 + (lane << 2));
        ushort4 u5 = *(const ushort4*)(h1b + (size_t)sc5 * C1 + (lane << 2));
        ushort4 u6 = *(const ushort4*)(h1b + (size_t)sc6 * C1 + (lane << 2));
        ushort4 u7 = *(const ushort4*)(h1b + (size_t)sc7 * C1 + (lane << 2));
        float p0 = __expf(leaky(als[sc0 * NHEAD + h] + ad));
        float p1 = __expf(leaky(als[sc1 * NHEAD + h] + ad));
        float p2 = __expf(leaky(als[sc2 * NHEAD + h] + ad));
        float p3 = __expf(leaky(als[sc3 * NHEAD + h] + ad));
        float p4 = __expf(leaky(als[sc4 * NHEAD + h] + ad));
        float p5 = __expf(leaky(als[sc5 * NHEAD + h] + ad));
        float p6 = __expf(leaky(als[sc6 * NHEAD + h] + ad));
        float p7 = __expf(leaky(als[sc7 * NHEAD + h] + ad));
        s += ((p0 + p1) + (p2 + p3)) + ((p4 + p5) + (p6 + p7));
        acc.x += ((p0*bf2f(u0.x) + p1*bf2f(u1.x)) + (p2*bf2f(u2.x) + p3*bf2f(u3.x)))
               + ((p4*bf2f(u4.x) + p5*bf2f(u5.x)) + (p6*bf2f(u6.x) + p7*bf2f(u7.x)));
        acc.y += ((p0*bf2f(u0.y) + p1*bf2f(u1.y)) + (p2*bf2f(u2.y) + p3*bf2f(u3.y)))
               + ((p4*bf2f(u4.y) + p5*bf2f(u5.y)) + (p6*bf2f(u6.y) + p7*bf2f(u7.y)));
        acc.z += ((p0*bf2f(u0.z) + p1*bf2f(u1.z)) + (p2*bf2f(u2.z) + p3*bf2f(u3.z)))
               + ((p4*bf2f(u4.z) + p5*bf2f(u5.z)) + (p6*bf2f(u6.z) + p7*bf2f(u7.z)));
        acc.w += ((p0*bf2f(u0.w) + p1*bf2f(u1.w)) + (p2*bf2f(u2.w) + p3*bf2f(u3.w)))
               + ((p4*bf2f(u4.w) + p5*bf2f(u5.w)) + (p6*bf2f(u6.w) + p7*bf2f(u7.w)));
    }
    for (; i + 3 < r1; i += 4){
        int sc0 = csr[i], sc1 = csr[i+1], sc2 = csr[i+2], sc3 = csr[i+3];
        ushort4 u0 = *(const ushort4*)(h1b + (size_t)sc0 * C1 + (lane << 2));
        ushort4 u1 = *(const ushort4*)(h1b + (size_t)sc1 * C1 + (lane << 2));
        ushort4 u2 = *(const ushort4*)(h1b + (size_t)sc2 * C1 + (lane << 2));
        ushort4 u3 = *(const ushort4*)(h1b + (size_t)sc3 * C1 + (lane << 2));
        float p0 = __expf(leaky(als[sc0 * NHEAD + h] + ad));
        float p1 = __expf(leaky(als[sc1 * NHEAD + h] + ad));
        float p2 = __expf(leaky(als[sc2 * NHEAD + h] + ad));
        float p3 = __expf(leaky(als[sc3 * NHEAD + h] + ad));
        s += (p0 + p1) + (p2 + p3);
        acc.x += (p0*bf2f(u0.x) + p1*bf2f(u1.x)) + (p2*bf2f(u2.x) + p3*bf2f(u3.x));
        acc.y += (p0*bf2f(u0.y) + p1*bf2f(u1.y)) + (p2*bf2f(u2.y) + p3*bf2f(u3.y));
        acc.z += (p0*bf2f(u0.z) + p1*bf2f(u1.z)) + (p2*bf2f(u2.z) + p3*bf2f(u3.z));
        acc.w += (p0*bf2f(u0.w) + p1*bf2f(u1.w)) + (p2*bf2f(u2.w) + p3*bf2f(u3.w));
    }
    for (; i < r1; i++){
        int sc = csr[i];
        ushort4 u = *(const ushort4*)(h1b + (size_t)sc * C1 + (lane << 2));
        float p = __expf(leaky(als[sc * NHEAD + h] + ad));
        s += p;
        acc.x += p * bf2f(u.x);
        acc.y += p * bf2f(u.y);
        acc.z += p * bf2f(u.z);
        acc.w += p * bf2f(u.w);
    }
    float sinv = 1.f / s;
    float4 b = *(const float4*)(b1 + (lane << 2));
    ushort4 ob;
    ob.x = bf16rne(elu1(acc.x * sinv + b.x));
    ob.y = bf16rne(elu1(acc.y * sinv + b.y));
    ob.z = bf16rne(elu1(acc.z * sinv + b.z));
    ob.w = bf16rne(elu1(acc.w * sinv + b.w));
    *(ushort4*)(hact_b + (size_t)node * C1 + (lane << 2)) = ob;
}

// ---------------- conv2 aggregation: fixed-ref softmax, bf16 gather, 8x MLP ----------------
__global__ __launch_bounds__(256) void k_agg2(const int* __restrict__ rowptr, const int* __restrict__ csr,
                       const unsigned short* __restrict__ h2b, const float* __restrict__ als,
                       const float* __restrict__ ald, const float* __restrict__ b2,
                       float* __restrict__ out){
    int gid = blockIdx.x * blockDim.x + threadIdx.x;
    int node = gid >> 6, lane = gid & 63;
    if (node >= N_NODES) return;
    float ad = ald[node];
    int r0 = rowptr[node], r1 = rowptr[node + 1];
    float s = 0.f, acc = 0.f;
    int i = r0;
    for (; i + 7 < r1; i += 8){
        int sc0 = csr[i],   sc1 = csr[i+1], sc2 = csr[i+2], sc3 = csr[i+3];
        int sc4 = csr[i+4], sc5 = csr[i+5], sc6 = csr[i+6], sc7 = csr[i+7];
        float f0 = bf2f(h2b[(size_t)sc0 * C2 + lane]);
        float f1 = bf2f(h2b[(size_t)sc1 * C2 + lane]);
        float f2 = bf2f(h2b[(size_t)sc2 * C2 + lane]);
        float f3 = bf2f(h2b[(size_t)sc3 * C2 + lane]);
        float f4 = bf2f(h2b[(size_t)sc4 * C2 + lane]);
        float f5 = bf2f(h2b[(size_t)sc5 * C2 + lane]);
        float f6 = bf2f(h2b[(size_t)sc6 * C2 + lane]);
        float f7 = bf2f(h2b[(size_t)sc7 * C2 + lane]);
        float p0 = __expf(leaky(als[sc0] + ad));
        float p1 = __expf(leaky(als[sc1] + ad));
        float p2 = __expf(leaky(als[sc2] + ad));
        float p3 = __expf(leaky(als[sc3] + ad));
        float p4 = __expf(leaky(als[sc4] + ad));
        float p5 = __expf(leaky(als[sc5] + ad));
        float p6 = __expf(leaky(als[sc6] + ad));
        float p7 = __expf(leaky(als[sc7] + ad));
        s += ((p0 + p1) + (p2 + p3)) + ((p4 + p5) + (p6 + p7));
        acc += ((p0*f0 + p1*f1) + (p2*f2 + p3*f3)) + ((p4*f4 + p5*f5) + (p6*f6 + p7*f7));
    }
    for (; i + 3 < r1; i += 4){
        int sc0 = csr[i], sc1 = csr[i+1], sc2 = csr[i+2], sc3 = csr[i+3];
        float f0 = bf2f(h2b[(size_t)sc0 * C2 + lane]);
        float f1 = bf2f(h2b[(size_t)sc1 * C2 + lane]);
        float f2 = bf2f(h2b[(size_t)sc2 * C2 + lane]);
        float f3 = bf2f(h2b[(size_t)sc3 * C2 + lane]);
        float p0 = __expf(leaky(als[sc0] + ad));
        float p1 = __expf(leaky(als[sc1] + ad));
        float p2 = __expf(leaky(als[sc2] + ad));
        float p3 = __expf(leaky(als[sc3] + ad));
        s += (p0 + p1) + (p2 + p3);
        acc += (p0*f0 + p1*f1) + (p2*f2 + p3*f3);
    }
    for (; i < r1; i++){
        int sc = csr[i];
        float f = bf2f(h2b[(size_t)sc * C2 + lane]);
        float p = __expf(leaky(als[sc] + ad));
        s += p;
        acc += p * f;
    }
    out[(size_t)node * C2 + lane] = elu1(acc / s + b2[lane]);
}

extern "C" void kernel_launch(void* const* d_in, const int* in_sizes, int n_in,
                              void* d_out, int out_size, void* d_ws, size_t ws_size,
                              hipStream_t stream) {
    const float* x      = (const float*)d_in[0];
    const int*   ei     = (const int*)d_in[1];
    const float* W1     = (const float*)d_in[2];
    const float* a_src1 = (const float*)d_in[3];
    const float* a_dst1 = (const float*)d_in[4];
    const float* b1     = (const float*)d_in[5];
    const float* W2     = (const float*)d_in[6];
    const float* a_src2 = (const float*)d_in[7];
    const float* a_dst2 = (const float*)d_in[8];
    const float* b2     = (const float*)d_in[9];
    float* out = (float*)d_out;

    const int* e_src = ei;
    const int* e_dst = ei + E_EDGES;

    // ---- workspace layout (float units) ----
    float* ws = (float*)d_ws;
    unsigned short* h1b = (unsigned short*)ws;                       // N*256 bf16 (6.4M f)
    float* als1 = ws + (size_t)N_NODES * C1 / 2;
    float* ald1 = als1 + (size_t)N_NODES * NHEAD;
    unsigned short* hact_b = (unsigned short*)(ald1 + (size_t)N_NODES * NHEAD); // N*256 bf16
    float* als2 = (float*)(hact_b + (size_t)N_NODES * C1);
    float* ald2 = als2 + N_NODES;
    unsigned short* xb  = (unsigned short*)(ald2 + N_NODES);         // N*128 bf16 (3.2M f)
    unsigned short* W1T = xb + (size_t)N_NODES * IN_DIM;             // 32768
    unsigned short* W2T = W1T + C1 * IN_DIM;                         // 16384
    float* iend = (float*)(W2T + C2 * C1);
    int* deg    = (int*)iend;
    int* rowptr = deg + N_NODES;
    int* cursor = rowptr + N_NODES + 1;
    int* bsum   = cursor + N_NODES;
    int* csr    = bsum + NBLK;
    // h2b aliases h1b region (h1b dead after agg1)
    unsigned short* h2b = h1b;

    // ---- prep casts ----
    k_castx<<<(N_NODES * IN_DIM / 4 + 255) / 256, 256, 0, stream>>>(x, xb);
    k_wtrans<<<(C1 * IN_DIM + C2 * C1 + 255) / 256, 256, 0, stream>>>(W1, W2, W1T, W2T);

    // ---- CSR build ----
    hipMemsetAsync(deg, 0, N_NODES * sizeof(int), stream);
    k_count<<<(E_EDGES + 255) / 256, 256, 0, stream>>>(e_dst, deg);
    k_block_scan<<<NBLK, 256, 0, stream>>>(deg, rowptr, bsum);
    k_scan_sums<<<1, 256, 0, stream>>>(bsum, rowptr);
    k_add_off<<<NBLK, 256, 0, stream>>>(bsum, rowptr, cursor);
    k_scatter<<<(E_TOT + 255) / 256, 256, 0, stream>>>(e_src, e_dst, cursor, csr);

    // ---- conv1 ----
    k_gemm1<<<dim3(391, 2), 256, 0, stream>>>(xb, W1T, a_src1, a_dst1, h1b, als1, ald1);
    k_agg1<<<(N_NODES * 64 + 255) / 256, 256, 0, stream>>>(rowptr, csr, h1b, als1, ald1, b1, hact_b);

    // ---- conv2 ----
    k_gemm2<<<391, 256, 0, stream>>>(hact_b, W2T, a_src2, a_dst2, h2b, als2, ald2);
    k_agg2<<<(N_NODES * 64 + 255) / 256, 256, 0, stream>>>(rowptr, csr, h2b, als2, ald2, b2, out);
}

// Round 12
// 302.629 us; speedup vs baseline: 1.2648x; 1.0719x over previous
//
#include <hip/hip_runtime.h>

#define N_NODES 50000
#define E_EDGES 800000
#define E_TOT   850000   // E + N self loops
#define IN_DIM  128
#define C1      256      // H1*HID
#define NHEAD   8
#define HID     32
#define C2      64
#define NEG     0.2f
#define NBLK    196      // ceil(50000/256)

// k_prep partition
#define CAST_BLKS 6250   // N*128/4/256
#define WT_BLKS   192    // (C1*IN_DIM + C2*C1)/256
#define CNT_BLKS  3125   // E/256
// k_gemm1_scatter partition
#define G1_BLKS   782    // 391*2
#define SCT_BLKS  3321   // ceil(E_TOT/256)

typedef __attribute__((ext_vector_type(8))) short short8_t;   // 8 bf16 (4 VGPRs)
typedef __attribute__((ext_vector_type(4))) float f32x4_t;    // MFMA acc

__device__ __forceinline__ float leaky(float x){ return x > 0.f ? x : NEG * x; }
__device__ __forceinline__ float elu1(float x){ return x > 0.f ? x : __expf(x) - 1.f; }
__device__ __forceinline__ unsigned short bf16rne(float v){
    unsigned int b = __float_as_uint(v);
    b += 0x7FFFu + ((b >> 16) & 1u);
    return (unsigned short)(b >> 16);
}
__device__ __forceinline__ float bf2f(unsigned short u){
    return __uint_as_float((unsigned int)u << 16);
}

// ---------------- prep: castx || wtrans || count, one launch ----------------
__global__ __launch_bounds__(256) void k_prep(const float* __restrict__ x,
                                              const float* __restrict__ W1,
                                              const float* __restrict__ W2,
                                              const int* __restrict__ dst,
                                              unsigned short* __restrict__ xb,
                                              unsigned short* __restrict__ W1T,
                                              unsigned short* __restrict__ W2T,
                                              int* __restrict__ deg){
    int bid = blockIdx.x;
    if (bid < CAST_BLKS){
        int i = bid * 256 + threadIdx.x;
        if (i < N_NODES * IN_DIM / 4){
            float4 v = *(const float4*)(x + (size_t)i * 4);
            ushort4 o;
            o.x = bf16rne(v.x); o.y = bf16rne(v.y); o.z = bf16rne(v.z); o.w = bf16rne(v.w);
            *(ushort4*)(xb + (size_t)i * 4) = o;
        }
    } else if (bid < CAST_BLKS + WT_BLKS){
        int i = (bid - CAST_BLKS) * 256 + threadIdx.x;
        if (i < C1 * IN_DIM){
            int n = i >> 7, k = i & 127;
            W1T[i] = bf16rne(W1[k * C1 + n]);
        } else {
            int j = i - C1 * IN_DIM;
            if (j < C2 * C1){
                int n = j >> 8, k = j & 255;
                W2T[j] = bf16rne(W2[k * C2 + n]);
            }
        }
    } else {
        int e = (bid - CAST_BLKS - WT_BLKS) * 256 + threadIdx.x;
        if (e < E_EDGES) atomicAdd(&deg[dst[e]], 1);
    }
}

// ---------------- CSR: per-block scan ----------------
__global__ __launch_bounds__(256) void k_block_scan(const int* __restrict__ deg,
                                                    int* __restrict__ rowptr,
                                                    int* __restrict__ bsum){
    __shared__ int sd[256];
    const int t = threadIdx.x;
    int i = blockIdx.x * 256 + t;
    int v = (i < N_NODES) ? (deg[i] + 1) : 0;   // +1 for self loop
    sd[t] = v;
    __syncthreads();
    #pragma unroll
    for (int off = 1; off < 256; off <<= 1){
        int u = (t >= off) ? sd[t - off] : 0;
        __syncthreads();
        sd[t] += u;
        __syncthreads();
    }
    if (i < N_NODES) rowptr[i] = sd[t] - v;
    if (t == 255) bsum[blockIdx.x] = sd[255];
}

// ---------------- CSR: add block offsets (each block scans bsum itself) ----------------
__global__ __launch_bounds__(256) void k_add_off2(const int* __restrict__ bsum,
                                                  int* __restrict__ rowptr,
                                                  int* __restrict__ cursor){
    __shared__ int sd[256];
    const int t = threadIdx.x;
    int v = (t < NBLK) ? bsum[t] : 0;
    sd[t] = v;
    __syncthreads();
    #pragma unroll
    for (int off = 1; off < 256; off <<= 1){
        int u = (t >= off) ? sd[t - off] : 0;
        __syncthreads();
        sd[t] += u;
        __syncthreads();
    }
    int bid = blockIdx.x;
    int boff = (bid == 0) ? 0 : sd[bid - 1];
    int i = bid * 256 + t;
    if (i < N_NODES){
        int r = rowptr[i] + boff;
        rowptr[i] = r;
        cursor[i] = r;
    }
    if (bid == 0 && t == 0) rowptr[N_NODES] = sd[NBLK - 1];
}

// ---------------- GEMM1 (bf16 MFMA) || scatter, one launch ----------------
__global__ __launch_bounds__(256) void k_gemm1_scatter(
        const unsigned short* __restrict__ xb,
        const unsigned short* __restrict__ W1T,
        const float* __restrict__ a_src,
        const float* __restrict__ a_dst,
        unsigned short* __restrict__ h1b,
        float* __restrict__ als,
        float* __restrict__ ald,
        const int* __restrict__ e_src,
        const int* __restrict__ e_dst,
        int* __restrict__ cursor,
        int* __restrict__ csr){
    __shared__ unsigned short As[128][136];
    __shared__ unsigned short Bs[128][136];
    const int bid = blockIdx.x;
    if (bid >= G1_BLKS){
        // ---- scatter part ----
        int e = (bid - G1_BLKS) * 256 + threadIdx.x;
        if (e < E_EDGES){
            int p = atomicAdd(&cursor[e_dst[e]], 1);
            if (p < E_TOT) csr[p] = e_src[e];
        } else if (e < E_TOT){
            int nloc = e - E_EDGES;
            int p = atomicAdd(&cursor[nloc], 1);
            if (p < E_TOT) csr[p] = nloc;
        }
        return;
    }
    // ---- gemm1 part ----
    const int t = threadIdx.x;
    const int lane = t & 63, w = t >> 6;
    const int wr = w >> 1, wc = w & 1;
    const int bm0 = (bid >> 1) * 128, bn0 = (bid & 1) * 128;
    const int fr = lane & 15, fg = lane >> 4;

    #pragma unroll
    for (int p = 0; p < 8; p++){
        int idx = t + (p << 8);
        int r = idx >> 4, c = (idx & 15) << 3;
        int row = bm0 + r;
        int4 v = make_int4(0,0,0,0);
        if (row < N_NODES) v = *(const int4*)(xb + (size_t)row * IN_DIM + c);
        *(int4*)&As[r][c] = v;
        *(int4*)&Bs[r][c] = *(const int4*)(W1T + (size_t)(bn0 + r) * IN_DIM + c);
    }
    __syncthreads();

    f32x4_t acc[4][4] = {};
    #pragma unroll
    for (int kk = 0; kk < 4; kk++){
        short8_t af[4], bf[4];
        #pragma unroll
        for (int i = 0; i < 4; i++)
            af[i] = *(const short8_t*)&As[wr*64 + i*16 + fr][kk*32 + fg*8];
        #pragma unroll
        for (int j = 0; j < 4; j++)
            bf[j] = *(const short8_t*)&Bs[wc*64 + j*16 + fr][kk*32 + fg*8];
        #pragma unroll
        for (int i = 0; i < 4; i++)
            #pragma unroll
            for (int j = 0; j < 4; j++)
                acc[i][j] = __builtin_amdgcn_mfma_f32_16x16x32_bf16(af[i], bf[j], acc[i][j], 0, 0, 0);
    }

    float asv[4], adv[4];
    #pragma unroll
    for (int j = 0; j < 4; j++){
        int col = bn0 + wc*64 + j*16 + fr;
        asv[j] = a_src[col];
        adv[j] = a_dst[col];
    }
    #pragma unroll
    for (int i = 0; i < 4; i++){
        #pragma unroll
        for (int hp = 0; hp < 2; hp++){
            #pragma unroll
            for (int reg = 0; reg < 4; reg++){
                float ps = acc[i][2*hp][reg]*asv[2*hp] + acc[i][2*hp+1][reg]*asv[2*hp+1];
                float pd = acc[i][2*hp][reg]*adv[2*hp] + acc[i][2*hp+1][reg]*adv[2*hp+1];
                ps += __shfl_xor(ps, 1, 64); ps += __shfl_xor(ps, 2, 64);
                ps += __shfl_xor(ps, 4, 64); ps += __shfl_xor(ps, 8, 64);
                pd += __shfl_xor(pd, 1, 64); pd += __shfl_xor(pd, 2, 64);
                pd += __shfl_xor(pd, 4, 64); pd += __shfl_xor(pd, 8, 64);
                int R = bm0 + wr*64 + i*16 + fg*4 + reg;
                if (fr == 0 && R < N_NODES){
                    int hd = (bn0 >> 5) + wc*2 + hp;
                    als[R * NHEAD + hd] = ps;
                    ald[R * NHEAD + hd] = pd;
                }
            }
        }
        #pragma unroll
        for (int reg = 0; reg < 4; reg++){
            int R = bm0 + wr*64 + i*16 + fg*4 + reg;
            if (R < N_NODES){
                #pragma unroll
                for (int j = 0; j < 4; j++)
                    h1b[(size_t)R * C1 + bn0 + wc*64 + j*16 + fr] = bf16rne(acc[i][j][reg]);
            }
        }
    }
}

// ---------------- GEMM2 (hact_b@W2, bf16 MFMA): 128x64 tile, fused scores + bf16 out ----------------
__global__ __launch_bounds__(256) void k_gemm2(const unsigned short* __restrict__ A,
                                               const unsigned short* __restrict__ W2T,
                                               const float* __restrict__ a_src,
                                               const float* __restrict__ a_dst,
                                               unsigned short* __restrict__ h2b,
                                               float* __restrict__ als,
                                               float* __restrict__ ald){
    __shared__ unsigned short As[128][136];
    __shared__ unsigned short Bs[64][136];
    const int t = threadIdx.x;
    const int lane = t & 63, w = t >> 6;
    const int bm0 = blockIdx.x * 128;
    const int fr = lane & 15, fg = lane >> 4;

    f32x4_t acc[2][4] = {};
    for (int kh = 0; kh < 2; kh++){
        #pragma unroll
        for (int p = 0; p < 8; p++){
            int idx = t + (p << 8);
            int r = idx >> 4, c = (idx & 15) << 3;
            int row = bm0 + r;
            int4 v = make_int4(0,0,0,0);
            if (row < N_NODES) v = *(const int4*)(A + (size_t)row * C1 + kh*128 + c);
            *(int4*)&As[r][c] = v;
        }
        #pragma unroll
        for (int p = 0; p < 4; p++){
            int idx = t + (p << 8);
            int r = idx >> 4, c = (idx & 15) << 3;
            *(int4*)&Bs[r][c] = *(const int4*)(W2T + (size_t)r * C1 + kh*128 + c);
        }
        __syncthreads();
        #pragma unroll
        for (int kk = 0; kk < 4; kk++){
            short8_t af[2], bf[4];
            #pragma unroll
            for (int i = 0; i < 2; i++)
                af[i] = *(const short8_t*)&As[w*32 + i*16 + fr][kk*32 + fg*8];
            #pragma unroll
            for (int j = 0; j < 4; j++)
                bf[j] = *(const short8_t*)&Bs[j*16 + fr][kk*32 + fg*8];
            #pragma unroll
            for (int i = 0; i < 2; i++)
                #pragma unroll
                for (int j = 0; j < 4; j++)
                    acc[i][j] = __builtin_amdgcn_mfma_f32_16x16x32_bf16(af[i], bf[j], acc[i][j], 0, 0, 0);
        }
        __syncthreads();
    }

    float asv[4], adv[4];
    #pragma unroll
    for (int j = 0; j < 4; j++){
        int col = j*16 + fr;
        asv[j] = a_src[col];
        adv[j] = a_dst[col];
    }
    #pragma unroll
    for (int i = 0; i < 2; i++){
        #pragma unroll
        for (int reg = 0; reg < 4; reg++){
            float ps = acc[i][0][reg]*asv[0] + acc[i][1][reg]*asv[1]
                     + acc[i][2][reg]*asv[2] + acc[i][3][reg]*asv[3];
            float pd = acc[i][0][reg]*adv[0] + acc[i][1][reg]*adv[1]
                     + acc[i][2][reg]*adv[2] + acc[i][3][reg]*adv[3];
            ps += __shfl_xor(ps, 1, 64); ps += __shfl_xor(ps, 2, 64);
            ps += __shfl_xor(ps, 4, 64); ps += __shfl_xor(ps, 8, 64);
            pd += __shfl_xor(pd, 1, 64); pd += __shfl_xor(pd, 2, 64);
            pd += __shfl_xor(pd, 4, 64); pd += __shfl_xor(pd, 8, 64);
            int R = bm0 + w*32 + i*16 + fg*4 + reg;
            if (fr == 0 && R < N_NODES){
                als[R] = ps;
                ald[R] = pd;
            }
            if (R < N_NODES){
                #pragma unroll
                for (int j = 0; j < 4; j++)
                    h2b[(size_t)R * C2 + j*16 + fr] = bf16rne(acc[i][j][reg]);
            }
        }
    }
}

// ---------------- conv1 aggregation: fixed-ref softmax, bf16 gather, 8x MLP ----------------
__global__ __launch_bounds__(256) void k_agg1(const int* __restrict__ rowptr, const int* __restrict__ csr,
                       const unsigned short* __restrict__ h1b, const float* __restrict__ als,
                       const float* __restrict__ ald, const float* __restrict__ b1,
                       unsigned short* __restrict__ hact_b){
    int gid = blockIdx.x * blockDim.x + threadIdx.x;
    int node = gid >> 6, lane = gid & 63;
    if (node >= N_NODES) return;
    int h = lane >> 3;
    float ad = ald[node * NHEAD + h];
    int r0 = rowptr[node], r1 = rowptr[node + 1];
    float s = 0.f;
    float4 acc = make_float4(0.f, 0.f, 0.f, 0.f);
    int i = r0;
    for (; i + 7 < r1; i += 8){
        int sc0 = csr[i],   sc1 = csr[i+1], sc2 = csr[i+2], sc3 = csr[i+3];
        int sc4 = csr[i+4], sc5 = csr[i+5], sc6 = csr[i+6], sc7 = csr[i+7];
        ushort4 u0 = *(const ushort4*)(h1b + (size_t)sc0 * C1 + (lane << 2));
        ushort4 u1 = *(const ushort4*)(h1b + (size_t)sc1 * C1 + (lane << 2));
        ushort4 u2 = *(const ushort4*)(h1b + (size_t)sc2 * C1 + (lane << 2));
        ushort4 u3 = *(const ushort4*)(h1b + (size_t)sc3 * C1 + (lane << 2));
        ushort4 u4 = *(const ushort4*)(h1b + (size_t)sc4 * C1 + (lane << 2));
        ushort4 u5 = *(const ushort4*)(h1b + (size_t)sc5 * C1 + (lane << 2));
        ushort4 u6 = *(const ushort4*)(h1b + (size_t)sc6 * C1 + (lane << 2));
        ushort4 u7 = *(const ushort4*)(h1b + (size_t)sc7 * C1 + (lane << 2));
        float p0 = __expf(leaky(als[sc0 * NHEAD + h] + ad));
        float p1 = __expf(leaky(als[sc1 * NHEAD + h] + ad));
        float p2 = __expf(leaky(als[sc2 * NHEAD + h] + ad));
        float p3 = __expf(leaky(als[sc3 * NHEAD + h] + ad));
        float p4 = __expf(leaky(als[sc4 * NHEAD + h] + ad));
        float p5 = __expf(leaky(als[sc5 * NHEAD + h] + ad));
        float p6 = __expf(leaky(als[sc6 * NHEAD + h] + ad));
        float p7 = __expf(leaky(als[sc7 * NHEAD + h] + ad));
        s += ((p0 + p1) + (p2 + p3)) + ((p4 + p5) + (p6 + p7));
        acc.x += ((p0*bf2f(u0.x) + p1*bf2f(u1.x)) + (p2*bf2f(u2.x) + p3*bf2f(u3.x)))
               + ((p4*bf2f(u4.x) + p5*bf2f(u5.x)) + (p6*bf2f(u6.x) + p7*bf2f(u7.x)));
        acc.y += ((p0*bf2f(u0.y) + p1*bf2f(u1.y)) + (p2*bf2f(u2.y) + p3*bf2f(u3.y)))
               + ((p4*bf2f(u4.y) + p5*bf2f(u5.y)) + (p6*bf2f(u6.y) + p7*bf2f(u7.y)));
        acc.z += ((p0*bf2f(u0.z) + p1*bf2f(u1.z)) + (p2*bf2f(u2.z) + p3*bf2f(u3.z)))
               + ((p4*bf2f(u4.z) + p5*bf2f(u5.z)) + (p6*bf2f(u6.z) + p7*bf2f(u7.z)));
        acc.w += ((p0*bf2f(u0.w) + p1*bf2f(u1.w)) + (p2*bf2f(u2.w) + p3*bf2f(u3.w)))
               + ((p4*bf2f(u4.w) + p5*bf2f(u5.w)) + (p6*bf2f(u6.w) + p7*bf2f(u7.w)));
    }
    for (; i + 3 < r1; i += 4){
        int sc0 = csr[i], sc1 = csr[i+1], sc2 = csr[i+2], sc3 = csr[i+3];
        ushort4 u0 = *(const ushort4*)(h1b + (size_t)sc0 * C1 + (lane << 2));
        ushort4 u1 = *(const ushort4*)(h1b + (size_t)sc1 * C1 + (lane << 2));
        ushort4 u2 = *(const ushort4*)(h1b + (size_t)sc2 * C1 + (lane << 2));
        ushort4 u3 = *(const ushort4*)(h1b + (size_t)sc3 * C1 + (lane << 2));
        float p0 = __expf(leaky(als[sc0 * NHEAD + h] + ad));
        float p1 = __expf(leaky(als[sc1 * NHEAD + h] + ad));
        float p2 = __expf(leaky(als[sc2 * NHEAD + h] + ad));
        float p3 = __expf(leaky(als[sc3 * NHEAD + h] + ad));
        s += (p0 + p1) + (p2 + p3);
        acc.x += (p0*bf2f(u0.x) + p1*bf2f(u1.x)) + (p2*bf2f(u2.x) + p3*bf2f(u3.x));
        acc.y += (p0*bf2f(u0.y) + p1*bf2f(u1.y)) + (p2*bf2f(u2.y) + p3*bf2f(u3.y));
        acc.z += (p0*bf2f(u0.z) + p1*bf2f(u1.z)) + (p2*bf2f(u2.z) + p3*bf2f(u3.z));
        acc.w += (p0*bf2f(u0.w) + p1*bf2f(u1.w)) + (p2*bf2f(u2.w) + p3*bf2f(u3.w));
    }
    for (; i < r1; i++){
        int sc = csr[i];
        ushort4 u = *(const ushort4*)(h1b + (size_t)sc * C1 + (lane << 2));
        float p = __expf(leaky(als[sc * NHEAD + h] + ad));
        s += p;
        acc.x += p * bf2f(u.x);
        acc.y += p * bf2f(u.y);
        acc.z += p * bf2f(u.z);
        acc.w += p * bf2f(u.w);
    }
    float sinv = 1.f / s;
    float4 b = *(const float4*)(b1 + (lane << 2));
    ushort4 ob;
    ob.x = bf16rne(elu1(acc.x * sinv + b.x));
    ob.y = bf16rne(elu1(acc.y * sinv + b.y));
    ob.z = bf16rne(elu1(acc.z * sinv + b.z));
    ob.w = bf16rne(elu1(acc.w * sinv + b.w));
    *(ushort4*)(hact_b + (size_t)node * C1 + (lane << 2)) = ob;
}

// ---------------- conv2 aggregation: fixed-ref softmax, bf16 gather, 8x MLP ----------------
__global__ __launch_bounds__(256) void k_agg2(const int* __restrict__ rowptr, const int* __restrict__ csr,
                       const unsigned short* __restrict__ h2b, const float* __restrict__ als,
                       const float* __restrict__ ald, const float* __restrict__ b2,
                       float* __restrict__ out){
    int gid = blockIdx.x * blockDim.x + threadIdx.x;
    int node = gid >> 6, lane = gid & 63;
    if (node >= N_NODES) return;
    float ad = ald[node];
    int r0 = rowptr[node], r1 = rowptr[node + 1];
    float s = 0.f, acc = 0.f;
    int i = r0;
    for (; i + 7 < r1; i += 8){
        int sc0 = csr[i],   sc1 = csr[i+1], sc2 = csr[i+2], sc3 = csr[i+3];
        int sc4 = csr[i+4], sc5 = csr[i+5], sc6 = csr[i+6], sc7 = csr[i+7];
        float f0 = bf2f(h2b[(size_t)sc0 * C2 + lane]);
        float f1 = bf2f(h2b[(size_t)sc1 * C2 + lane]);
        float f2 = bf2f(h2b[(size_t)sc2 * C2 + lane]);
        float f3 = bf2f(h2b[(size_t)sc3 * C2 + lane]);
        float f4 = bf2f(h2b[(size_t)sc4 * C2 + lane]);
        float f5 = bf2f(h2b[(size_t)sc5 * C2 + lane]);
        float f6 = bf2f(h2b[(size_t)sc6 * C2 + lane]);
        float f7 = bf2f(h2b[(size_t)sc7 * C2 + lane]);
        float p0 = __expf(leaky(als[sc0] + ad));
        float p1 = __expf(leaky(als[sc1] + ad));
        float p2 = __expf(leaky(als[sc2] + ad));
        float p3 = __expf(leaky(als[sc3] + ad));
        float p4 = __expf(leaky(als[sc4] + ad));
        float p5 = __expf(leaky(als[sc5] + ad));
        float p6 = __expf(leaky(als[sc6] + ad));
        float p7 = __expf(leaky(als[sc7] + ad));
        s += ((p0 + p1) + (p2 + p3)) + ((p4 + p5) + (p6 + p7));
        acc += ((p0*f0 + p1*f1) + (p2*f2 + p3*f3)) + ((p4*f4 + p5*f5) + (p6*f6 + p7*f7));
    }
    for (; i + 3 < r1; i += 4){
        int sc0 = csr[i], sc1 = csr[i+1], sc2 = csr[i+2], sc3 = csr[i+3];
        float f0 = bf2f(h2b[(size_t)sc0 * C2 + lane]);
        float f1 = bf2f(h2b[(size_t)sc1 * C2 + lane]);
        float f2 = bf2f(h2b[(size_t)sc2 * C2 + lane]);
        float f3 = bf2f(h2b[(size_t)sc3 * C2 + lane]);
        float p0 = __expf(leaky(als[sc0] + ad));
        float p1 = __expf(leaky(als[sc1] + ad));
        float p2 = __expf(leaky(als[sc2] + ad));
        float p3 = __expf(leaky(als[sc3] + ad));
        s += (p0 + p1) + (p2 + p3);
        acc += (p0*f0 + p1*f1) + (p2*f2 + p3*f3);
    }
    for (; i < r1; i++){
        int sc = csr[i];
        float f = bf2f(h2b[(size_t)sc * C2 + lane]);
        float p = __expf(leaky(als[sc] + ad));
        s += p;
        acc += p * f;
    }
    out[(size_t)node * C2 + lane] = elu1(acc / s + b2[lane]);
}

extern "C" void kernel_launch(void* const* d_in, const int* in_sizes, int n_in,
                              void* d_out, int out_size, void* d_ws, size_t ws_size,
                              hipStream_t stream) {
    const float* x      = (const float*)d_in[0];
    const int*   ei     = (const int*)d_in[1];
    const float* W1     = (const float*)d_in[2];
    const float* a_src1 = (const float*)d_in[3];
    const float* a_dst1 = (const float*)d_in[4];
    const float* b1     = (const float*)d_in[5];
    const float* W2     = (const float*)d_in[6];
    const float* a_src2 = (const float*)d_in[7];
    const float* a_dst2 = (const float*)d_in[8];
    const float* b2     = (const float*)d_in[9];
    float* out = (float*)d_out;

    const int* e_src = ei;
    const int* e_dst = ei + E_EDGES;

    // ---- workspace layout (float units) ----
    float* ws = (float*)d_ws;
    unsigned short* h1b = (unsigned short*)ws;                       // N*256 bf16
    float* als1 = ws + (size_t)N_NODES * C1 / 2;
    float* ald1 = als1 + (size_t)N_NODES * NHEAD;
    unsigned short* hact_b = (unsigned short*)(ald1 + (size_t)N_NODES * NHEAD); // N*256 bf16
    float* als2 = (float*)(hact_b + (size_t)N_NODES * C1);
    float* ald2 = als2 + N_NODES;
    unsigned short* xb  = (unsigned short*)(ald2 + N_NODES);         // N*128 bf16
    unsigned short* W1T = xb + (size_t)N_NODES * IN_DIM;             // 32768
    unsigned short* W2T = W1T + C1 * IN_DIM;                         // 16384
    float* iend = (float*)(W2T + C2 * C1);
    int* deg    = (int*)iend;
    int* rowptr = deg + N_NODES;
    int* cursor = rowptr + N_NODES + 1;
    int* bsum   = cursor + N_NODES;
    int* csr    = bsum + NBLK;
    // h2b aliases h1b region (h1b dead after agg1)
    unsigned short* h2b = h1b;

    // 1. zero degree counters
    hipMemsetAsync(deg, 0, N_NODES * sizeof(int), stream);
    // 2. castx || wtrans || count
    k_prep<<<CAST_BLKS + WT_BLKS + CNT_BLKS, 256, 0, stream>>>(x, W1, W2, e_dst, xb, W1T, W2T, deg);
    // 3-4. CSR scan
    k_block_scan<<<NBLK, 256, 0, stream>>>(deg, rowptr, bsum);
    k_add_off2<<<NBLK, 256, 0, stream>>>(bsum, rowptr, cursor);
    // 5. gemm1 || scatter
    k_gemm1_scatter<<<G1_BLKS + SCT_BLKS, 256, 0, stream>>>(
        xb, W1T, a_src1, a_dst1, h1b, als1, ald1, e_src, e_dst, cursor, csr);
    // 6. conv1 aggregate
    k_agg1<<<(N_NODES * 64 + 255) / 256, 256, 0, stream>>>(rowptr, csr, h1b, als1, ald1, b1, hact_b);
    // 7. gemm2 (+ conv2 scores)
    k_gemm2<<<391, 256, 0, stream>>>(hact_b, W2T, a_src2, a_dst2, h2b, als2, ald2);
    // 8. conv2 aggregate
    k_agg2<<<(N_NODES * 64 + 255) / 256, 256, 0, stream>>>(rowptr, csr, h2b, als2, ald2, b2, out);
}